// Round 11
// baseline (709.290 us; speedup 1.0000x reference)
//
#include <hip/hip_runtime.h>
#include <hip/hip_bf16.h>
#include <stdint.h>
#include <stddef.h>

// B=2, T=2048, D=2048, H=16, DH=128, F=8192, M=B*T=4096
using bf16_t = __hip_bfloat16;
typedef __attribute__((ext_vector_type(8))) short short8;
typedef __attribute__((ext_vector_type(4))) float f32x4;

__device__ __forceinline__ void gload_lds16(const void* g, void* l) {
  __builtin_amdgcn_global_load_lds((const __attribute__((address_space(1))) void*)g,
                                   (__attribute__((address_space(3))) void*)l,
                                   16, 0, 0);
}

// ---------- transpose + f32->bf16 convert: out[N][K] = in[K][N] ----------
__global__ __launch_bounds__(256) void k_transpose_cvt(const float* __restrict__ in,
                                                       bf16_t* __restrict__ out,
                                                       int K, int N) {
  __shared__ float tile[64][65];
  int n0 = blockIdx.x * 64, k0 = blockIdx.y * 64;
  int t = threadIdx.x;
#pragma unroll
  for (int i = 0; i < 16; ++i) {
    int idx = t + i * 256;
    int kk = idx >> 6, nn = idx & 63;
    tile[kk][nn] = in[(size_t)(k0 + kk) * N + n0 + nn];
  }
  __syncthreads();
#pragma unroll
  for (int i = 0; i < 16; ++i) {
    int idx = t + i * 256;
    int nn = idx >> 6, kk = idx & 63;
    out[(size_t)(n0 + nn) * K + k0 + kk] = __float2bfloat16(tile[kk][nn]);
  }
}

// ---------- layernorm f32 -> bf16, one block per row of 2048 ----------
__global__ __launch_bounds__(256) void k_layernorm(const float* __restrict__ x,
                                                   const float* __restrict__ gam,
                                                   const float* __restrict__ bet,
                                                   bf16_t* __restrict__ out) {
  int row = blockIdx.x, t = threadIdx.x;
  const float4* xr = (const float4*)(x + (size_t)row * 2048);
  float4 a = xr[t], b = xr[t + 256];
  float s  = a.x + a.y + a.z + a.w + b.x + b.y + b.z + b.w;
  float s2 = a.x*a.x + a.y*a.y + a.z*a.z + a.w*a.w
           + b.x*b.x + b.y*b.y + b.z*b.z + b.w*b.w;
#pragma unroll
  for (int off = 32; off >= 1; off >>= 1) {
    s  += __shfl_xor(s, off);
    s2 += __shfl_xor(s2, off);
  }
  __shared__ float red[8];
  if ((t & 63) == 0) { red[t >> 6] = s; red[4 + (t >> 6)] = s2; }
  __syncthreads();
  float S  = red[0] + red[1] + red[2] + red[3];
  float S2 = red[4] + red[5] + red[6] + red[7];
  float mu = S * (1.0f / 2048.0f);
  float var = S2 * (1.0f / 2048.0f) - mu * mu;
  float rstd = rsqrtf(var + 1e-6f);
  const float4* gv = (const float4*)gam;
  const float4* bv = (const float4*)bet;
  float4 g1 = gv[t], g2 = gv[t + 256], c1 = bv[t], c2 = bv[t + 256];
  bf16_t* orow = out + (size_t)row * 2048;
  orow[4*t + 0]    = __float2bfloat16((a.x - mu) * rstd * g1.x + c1.x);
  orow[4*t + 1]    = __float2bfloat16((a.y - mu) * rstd * g1.y + c1.y);
  orow[4*t + 2]    = __float2bfloat16((a.z - mu) * rstd * g1.z + c1.z);
  orow[4*t + 3]    = __float2bfloat16((a.w - mu) * rstd * g1.w + c1.w);
  orow[1024 + 4*t + 0] = __float2bfloat16((b.x - mu) * rstd * g2.x + c2.x);
  orow[1024 + 4*t + 1] = __float2bfloat16((b.y - mu) * rstd * g2.y + c2.y);
  orow[1024 + 4*t + 2] = __float2bfloat16((b.z - mu) * rstd * g2.z + c2.z);
  orow[1024 + 4*t + 3] = __float2bfloat16((b.w - mu) * rstd * g2.w + c2.w);
}

// ---------- m97-structure GEMM: C[M,N] = A[M,K] x Bt[N,K] (bf16) ----------
// 128x128 tile, BK=32, 256 thr = 4 waves (2M x 2N), per-wave C = 64x64.
// SINGLE 16KB LDS buffer, two __syncthreads per K-step (compiler drains) —
// the measured-verified m97 recipe (874-912 TF): ~130 VGPR -> 3 waves/SIMD ->
// 3 BLOCKS/CU; cross-block TLP hides stage latency (m114), no choreography.
// L2-aware XCD mapping: XCD x owns m-tiles {4x..4x+3} (A-slice = 2MB, fits the
// 4MB per-XCD L2); n walks inner, 4 consecutive blocks share each B-tile.
// XOR chunk swizzle both sides (R6-verified, 0 conflicts).
// EPI: 0 = bf16+bias ; 1 = bf16+bias+gelu ; 3 = f32 atomicAdd (+bias on chunk 0).
template <int EPI>
__global__ __launch_bounds__(256, 3) void k_gemm9(const bf16_t* __restrict__ A,
                                                  const bf16_t* __restrict__ Bt,
                                                  const float* __restrict__ bias,
                                                  bf16_t* __restrict__ Cb,
                                                  float* __restrict__ Cf,
                                                  int Ndim, int LDA, int LDB,
                                                  int Kdim, int NTt, int nkch) {
  __shared__ __align__(16) bf16_t As[128 * 32];
  __shared__ __align__(16) bf16_t Bs[128 * 32];
  int orig = blockIdx.x;
  int xcd = orig & 7;                       // dispatch round-robins XCDs
  int r = orig >> 3;
  int perchunk = NTt * 4;                   // 4 m-tiles per XCD slice
  int chunk = r / perchunk;
  int r2 = r - chunk * perchunk;
  int m0 = (xcd * 4 + (r2 & 3)) * 128;      // M=4096 -> 32 m-tiles = 8 XCD x 4
  int n0 = (r2 >> 2) * 128;
  int tid = threadIdx.x;
  int w = tid >> 6, lane = tid & 63;
  int lr = lane & 15, lk = lane >> 4;
  int wr = w >> 1, wc = w & 1;
  const bf16_t* Ag = A + (size_t)m0 * LDA + (size_t)chunk * Kdim;
  const bf16_t* Bg = Bt + (size_t)n0 * LDB + (size_t)chunk * Kdim;

  // persistent staging pointers (2 rows per thread per matrix; +32 elems/K-step)
  int srow0 = tid >> 2, srow1 = srow0 + 64;
  int sc = tid & 3;
  const bf16_t* pA0 = Ag + (size_t)srow0 * LDA + ((sc ^ ((srow0 >> 1) & 3)) << 3);
  const bf16_t* pA1 = Ag + (size_t)srow1 * LDA + ((sc ^ ((srow1 >> 1) & 3)) << 3);
  const bf16_t* pB0 = Bg + (size_t)srow0 * LDB + ((sc ^ ((srow0 >> 1) & 3)) << 3);
  const bf16_t* pB1 = Bg + (size_t)srow1 * LDB + ((sc ^ ((srow1 >> 1) & 3)) << 3);
  int dst = tid * 16;                       // LDS linear dst (bytes)

  // loop-invariant swizzled read offsets (bf16 elems)
  int aoff[4], boff[4];
#pragma unroll
  for (int mf = 0; mf < 4; ++mf) {
    int row = wr * 64 + mf * 16 + lr;
    aoff[mf] = row * 32 + (lk ^ ((row >> 1) & 3)) * 8;
  }
#pragma unroll
  for (int nf = 0; nf < 4; ++nf) {
    int row = wc * 64 + nf * 16 + lr;
    boff[nf] = row * 32 + (lk ^ ((row >> 1) & 3)) * 8;
  }

  f32x4 acc[4][4];
#pragma unroll
  for (int i = 0; i < 4; ++i)
#pragma unroll
    for (int j = 0; j < 4; ++j) acc[i][j] = (f32x4){0.f, 0.f, 0.f, 0.f};

#define STG() do { \
    gload_lds16(pA0, (char*)As + dst);          \
    gload_lds16(pA1, (char*)As + 4096 + dst);   \
    gload_lds16(pB0, (char*)Bs + dst);          \
    gload_lds16(pB1, (char*)Bs + 4096 + dst);   \
    pA0 += 32; pA1 += 32; pB0 += 32; pB1 += 32; } while (0)

  const int NT = Kdim >> 5;
  STG();                                    // stage K-step 0
  for (int t = 0; t < NT; ++t) {
    __syncthreads();                        // drains vmcnt -> staged data visible
    short8 af[4], bf[4];
#pragma unroll
    for (int mf = 0; mf < 4; ++mf) af[mf] = *(const short8*)(As + aoff[mf]);
#pragma unroll
    for (int nf = 0; nf < 4; ++nf) bf[nf] = *(const short8*)(Bs + boff[nf]);
#pragma unroll
    for (int mf = 0; mf < 4; ++mf)
#pragma unroll
      for (int nf = 0; nf < 4; ++nf)
        acc[mf][nf] = __builtin_amdgcn_mfma_f32_16x16x32_bf16(af[mf], bf[nf], acc[mf][nf], 0, 0, 0);
    __syncthreads();                        // drains lgkm -> safe to overwrite
    if (t + 1 < NT) STG();
  }
#undef STG

  // epilogue: per-wave 64x64
#pragma unroll
  for (int mf = 0; mf < 4; ++mf) {
#pragma unroll
    for (int nf = 0; nf < 4; ++nf) {
#pragma unroll
      for (int r4 = 0; r4 < 4; ++r4) {
        int rw = m0 + wr * 64 + mf * 16 + lk * 4 + r4;
        int cl = n0 + wc * 64 + nf * 16 + lr;
        float v = acc[mf][nf][r4];
        size_t gi = (size_t)rw * Ndim + cl;
        if (EPI == 0) {
          Cb[gi] = __float2bfloat16(v + bias[cl]);
        } else if (EPI == 1) {
          float vv = v + bias[cl];
          float u = vv * (vv * vv * 0.044715f + 1.0f) * 0.7978845608028654f;
          float gl = 0.5f * vv * (1.0f + tanhf(u));
          Cb[gi] = __float2bfloat16(gl);
        } else {
          float add = v + (chunk == 0 ? bias[cl] : 0.0f);
          atomicAdd(&Cf[gi], add);
        }
      }
    }
  }
}

// ---------- transpose V slice of qkv into vT[b][h][dh][t] ----------
__global__ __launch_bounds__(256) void k_transpose_v(const bf16_t* __restrict__ qkv,
                                                     bf16_t* __restrict__ vT) {
  __shared__ bf16_t tile[64][72];
  int bid = blockIdx.x;
  int tt = bid & 31;
  int dt = (bid >> 5) & 1;
  int h  = (bid >> 6) & 15;
  int b  = bid >> 10;
  int t0 = tt * 64, d0 = dt * 64;
  int t = threadIdx.x;
  const bf16_t* src = qkv + (size_t)(b * 2048) * 6144 + 4096 + h * 128;
#pragma unroll
  for (int i = 0; i < 16; ++i) {
    int idx = t + i * 256;
    int rr = idx >> 6, cc = idx & 63;          // rr: t-dim, cc: d-dim
    tile[rr][cc] = src[(size_t)(t0 + rr) * 6144 + d0 + cc];
  }
  __syncthreads();
  bf16_t* dst = vT + (size_t)(b * 16 + h) * 128 * 2048;
#pragma unroll
  for (int i = 0; i < 16; ++i) {
    int idx = t + i * 256;
    int rr = idx >> 6, cc = idx & 63;          // rr: d-dim, cc: t-dim
    dst[(size_t)(d0 + rr) * 2048 + t0 + cc] = tile[cc][rr];
  }
}

// ---------- causal flash attention + residual add ----------
// One wave owns 32 q-rows. KBLK=32. 512 blocks x 4 waves; balanced chunks.
// R11: K/V loads software-pipelined — kf(t+1) issued right after QK^T(t)
// (kf dead), vf(t+1) right after PV(t) (vf dead); each load covered by
// ~one softmax+MFMA phase instead of being needed immediately.
__global__ __launch_bounds__(256, 2) void k_attn(const bf16_t* __restrict__ qkv,
                                                 const bf16_t* __restrict__ vT,
                                                 const float* __restrict__ x,
                                                 float* __restrict__ out) {
  __shared__ __align__(16) bf16_t Pl[4][32][40];   // per-wave P bounce, stride 40
  int j = blockIdx.x;
  int bh = j & 31;
  int cq = j >> 5;                                  // 0..15
  int b = bh >> 4, h = bh & 15;
  int w = threadIdx.x >> 6, lane = threadIdx.x & 63;
  int lr = lane & 15, lk = lane >> 4;
  int c = (w == 0) ? cq : (w == 1) ? (63 - cq) : (w == 2) ? (31 - cq) : (32 + cq);
  int q0 = c * 32;                                  // this wave's 32 q-rows
  const bf16_t* qb = qkv + (size_t)(b * 2048) * 6144 + h * 128;
  const bf16_t* kb = qb + 2048;
  const bf16_t* vb = vT + (size_t)(b * 16 + h) * 128 * 2048;
  short8 qf[2][4];
#pragma unroll
  for (int qg = 0; qg < 2; ++qg)
#pragma unroll
    for (int d4 = 0; d4 < 4; ++d4)
      qf[qg][d4] = *(const short8*)(qb + (size_t)(q0 + qg * 16 + lr) * 6144 + d4 * 32 + lk * 8);
  float m[2][4], l[2][4];
#pragma unroll
  for (int qg = 0; qg < 2; ++qg)
#pragma unroll
    for (int r = 0; r < 4; ++r) { m[qg][r] = -1e30f; l[qg][r] = 0.f; }
  f32x4 o[2][8] = {};
  int nkt = c + 1;
  const float sc = 0.08838834764831845f;           // 1/sqrt(128)
  // prologue loads (kt = 0)
  short8 kf[2][4], vf[8];
#pragma unroll
  for (int nt = 0; nt < 2; ++nt)
#pragma unroll
    for (int d4 = 0; d4 < 4; ++d4)
      kf[nt][d4] = *(const short8*)(kb + (size_t)(nt * 16 + lr) * 6144 + d4 * 32 + lk * 8);
#pragma unroll
  for (int d8 = 0; d8 < 8; ++d8)
    vf[d8] = *(const short8*)(vb + (size_t)(d8 * 16 + lr) * 2048 + lk * 8);

  for (int kt = 0; kt < nkt; ++kt) {
    int tk0 = kt * 32;
    // --- QK^T (consumes kf) ---
    f32x4 s[2][2] = {};
#pragma unroll
    for (int d4 = 0; d4 < 4; ++d4)
#pragma unroll
      for (int qg = 0; qg < 2; ++qg)
#pragma unroll
        for (int nt = 0; nt < 2; ++nt)
          s[qg][nt] = __builtin_amdgcn_mfma_f32_16x16x32_bf16(qf[qg][d4], kf[nt][d4], s[qg][nt], 0, 0, 0);
    // --- issue kf(t+1): covered by softmax + PV below ---
    if (kt + 1 < nkt) {
      int tn = tk0 + 32;
#pragma unroll
      for (int nt = 0; nt < 2; ++nt)
#pragma unroll
        for (int d4 = 0; d4 < 4; ++d4)
          kf[nt][d4] = *(const short8*)(kb + (size_t)(tn + nt * 16 + lr) * 6144 + d4 * 32 + lk * 8);
    }
    // --- online softmax ---
#pragma unroll
    for (int qg = 0; qg < 2; ++qg) {
      float sv[2][4], mt[4];
#pragma unroll
      for (int r = 0; r < 4; ++r) {
        int qr = q0 + qg * 16 + lk * 4 + r;
#pragma unroll
        for (int nt = 0; nt < 2; ++nt) {
          float v = s[qg][nt][r] * sc;
          int kc = tk0 + nt * 16 + lr;
          sv[nt][r] = (kc > qr) ? -1e30f : v;
        }
        mt[r] = fmaxf(sv[0][r], sv[1][r]);
      }
#pragma unroll
      for (int off = 1; off < 16; off <<= 1)
#pragma unroll
        for (int r = 0; r < 4; ++r) mt[r] = fmaxf(mt[r], __shfl_xor(mt[r], off));
      float alpha[4], rs[4];
#pragma unroll
      for (int r = 0; r < 4; ++r) {
        float mn = fmaxf(m[qg][r], mt[r]);
        alpha[r] = __expf(m[qg][r] - mn);
        m[qg][r] = mn;
      }
#pragma unroll
      for (int r = 0; r < 4; ++r) {
        float p0 = __expf(sv[0][r] - m[qg][r]);
        float p1 = __expf(sv[1][r] - m[qg][r]);
        rs[r] = p0 + p1;
        Pl[w][qg * 16 + lk * 4 + r][lr]      = __float2bfloat16(p0);
        Pl[w][qg * 16 + lk * 4 + r][16 + lr] = __float2bfloat16(p1);
      }
#pragma unroll
      for (int off = 1; off < 16; off <<= 1)
#pragma unroll
        for (int r = 0; r < 4; ++r) rs[r] += __shfl_xor(rs[r], off);
#pragma unroll
      for (int r = 0; r < 4; ++r) l[qg][r] = l[qg][r] * alpha[r] + rs[r];
#pragma unroll
      for (int d8 = 0; d8 < 8; ++d8)
#pragma unroll
        for (int r = 0; r < 4; ++r) o[qg][d8][r] *= alpha[r];
    }
    asm volatile("s_waitcnt lgkmcnt(0)" ::: "memory");
    short8 pf[2];
#pragma unroll
    for (int qg = 0; qg < 2; ++qg)
      pf[qg] = *(const short8*)(&Pl[w][qg * 16 + lr][lk * 8]);
    // --- PV (consumes vf) ---
#pragma unroll
    for (int d8 = 0; d8 < 8; ++d8)
#pragma unroll
      for (int qg = 0; qg < 2; ++qg)
        o[qg][d8] = __builtin_amdgcn_mfma_f32_16x16x32_bf16(pf[qg], vf[d8], o[qg][d8], 0, 0, 0);
    // --- issue vf(t+1): covered by QK^T + softmax of next iter ---
    if (kt + 1 < nkt) {
      int tn = tk0 + 32;
#pragma unroll
      for (int d8 = 0; d8 < 8; ++d8)
        vf[d8] = *(const short8*)(vb + (size_t)(d8 * 16 + lr) * 2048 + tn + lk * 8);
    }
  }
#pragma unroll
  for (int qg = 0; qg < 2; ++qg)
#pragma unroll
    for (int d8 = 0; d8 < 8; ++d8)
#pragma unroll
      for (int r = 0; r < 4; ++r) {
        int qr = q0 + qg * 16 + lk * 4 + r;
        int cl = h * 128 + d8 * 16 + lr;
        size_t gi = (size_t)(b * 2048 + qr) * 2048 + cl;
        out[gi] = x[gi] + o[qg][d8][r] / l[qg][r];
      }
}

extern "C" void kernel_launch(void* const* d_in, const int* in_sizes, int n_in,
                              void* d_out, int out_size, void* d_ws, size_t ws_size,
                              hipStream_t stream) {
  const float* x    = (const float*)d_in[0];
  const float* ln1s = (const float*)d_in[1];
  const float* ln1b = (const float*)d_in[2];
  const float* wqkv = (const float*)d_in[3];
  const float* bqkv = (const float*)d_in[4];
  const float* ln2s = (const float*)d_in[5];
  const float* ln2b = (const float*)d_in[6];
  const float* w1   = (const float*)d_in[7];
  const float* b1   = (const float*)d_in[8];
  const float* w2   = (const float*)d_in[9];
  const float* b2   = (const float*)d_in[10];
  float* out = (float*)d_out;
  char* ws = (char*)d_ws;

  // ws layout (bytes); r/vT share region 0 (disjoint lifetimes), wqkvT aliases h.
  bf16_t* r     = (bf16_t*)(ws + 0);              // 16,777,216  [4096][2048]
  bf16_t* vT    = (bf16_t*)(ws + 0);              // same region [2][16][128][2048]
  bf16_t* qkv   = (bf16_t*)(ws + 16777216);       // 50,331,648  [4096][6144]
  bf16_t* w1T   = (bf16_t*)(ws + 67108864);       // 33,554,432  [8192][2048]
  bf16_t* w2T   = (bf16_t*)(ws + 100663296);      // 33,554,432  [2048][8192]
  bf16_t* h     = (bf16_t*)(ws + 134217728);      // 67,108,864  [4096][8192]
  bf16_t* wqkvT = (bf16_t*)(ws + 134217728);      // 25,165,824  [6144][2048] (dead before h)
  // total required: 201,326,592 bytes

  // weight transposes (f32 [K][N] -> bf16 [N][K])
  k_transpose_cvt<<<dim3(96, 32),  256, 0, stream>>>(wqkv, wqkvT, 2048, 6144);
  k_transpose_cvt<<<dim3(128, 32), 256, 0, stream>>>(w1,   w1T,   2048, 8192);
  k_transpose_cvt<<<dim3(32, 128), 256, 0, stream>>>(w2,   w2T,   8192, 2048);
  // LN1
  k_layernorm<<<4096, 256, 0, stream>>>(x, ln1s, ln1b, r);
  // QKV: 32 m-tiles x 48 n-tiles = 1536 blocks (L2-aware mapping, NTt=48)
  k_gemm9<0><<<1536, 256, 0, stream>>>(r, wqkvT, bqkv, qkv, nullptr, 6144, 2048, 2048, 2048, 48, 1);
  // V transpose for PV operand
  k_transpose_v<<<2048, 256, 0, stream>>>(qkv, vT);
  // attention + residual (writes every element of d_out)
  k_attn<<<512, 256, 0, stream>>>(qkv, vT, x, out);
  // LN2 on x2 = d_out
  k_layernorm<<<4096, 256, 0, stream>>>(out, ln2s, ln2b, r);
  // MLP1: 32 x 64 = 2048 blocks (NTt=64)
  k_gemm9<1><<<2048, 256, 0, stream>>>(r, w1T, b1, h, nullptr, 8192, 2048, 2048, 2048, 64, 1);
  // MLP2 split-K=2, f32 atomicAdd epilogue (b2 on chunk 0): 32 x 16 x 2 = 1024 blocks
  k_gemm9<3><<<1024, 256, 0, stream>>>(h, w2T, b2, nullptr, out, 2048, 8192, 8192, 4096, 16, 2);
}

// Round 12
// 656.387 us; speedup vs baseline: 1.0806x; 1.0806x over previous
//
#include <hip/hip_runtime.h>
#include <hip/hip_bf16.h>
#include <stdint.h>
#include <stddef.h>

// B=2, T=2048, D=2048, H=16, DH=128, F=8192, M=B*T=4096
using bf16_t = __hip_bfloat16;
typedef __attribute__((ext_vector_type(8))) short short8;
typedef __attribute__((ext_vector_type(4))) short short4v;
typedef __attribute__((ext_vector_type(4))) float f32x4;

__device__ __forceinline__ void gload_lds16(const void* g, void* l) {
  __builtin_amdgcn_global_load_lds((const __attribute__((address_space(1))) void*)g,
                                   (__attribute__((address_space(3))) void*)l,
                                   16, 0, 0);
}

// ---------- transpose + f32->bf16 convert: out[N][K] = in[K][N] ----------
// R12: vectorized — float4 global loads, short4 global stores, scalar LDS hops
// ([64][65] pad -> <=2-way read conflicts).
__global__ __launch_bounds__(256) void k_transpose_cvt(const float* __restrict__ in,
                                                       bf16_t* __restrict__ out,
                                                       int K, int N) {
  __shared__ float tile[64][65];
  int n0 = blockIdx.x * 64, k0 = blockIdx.y * 64;
  int t = threadIdx.x;
  int tr = t >> 4, tc = t & 15;
#pragma unroll
  for (int i = 0; i < 4; ++i) {
    float4 v = *(const float4*)(in + (size_t)(k0 + tr + i * 16) * N + n0 + tc * 4);
    tile[tr + i * 16][tc * 4 + 0] = v.x;
    tile[tr + i * 16][tc * 4 + 1] = v.y;
    tile[tr + i * 16][tc * 4 + 2] = v.z;
    tile[tr + i * 16][tc * 4 + 3] = v.w;
  }
  __syncthreads();
#pragma unroll
  for (int i = 0; i < 4; ++i) {
    int nn = tr + i * 16;
    short4v s;
    s[0] = (short)__bfloat16_as_ushort(__float2bfloat16(tile[tc * 4 + 0][nn]));
    s[1] = (short)__bfloat16_as_ushort(__float2bfloat16(tile[tc * 4 + 1][nn]));
    s[2] = (short)__bfloat16_as_ushort(__float2bfloat16(tile[tc * 4 + 2][nn]));
    s[3] = (short)__bfloat16_as_ushort(__float2bfloat16(tile[tc * 4 + 3][nn]));
    *(short4v*)(out + (size_t)(n0 + nn) * K + k0 + tc * 4) = s;
  }
}

// ---------- layernorm f32 -> bf16, one block per row of 2048 ----------
__global__ __launch_bounds__(256) void k_layernorm(const float* __restrict__ x,
                                                   const float* __restrict__ gam,
                                                   const float* __restrict__ bet,
                                                   bf16_t* __restrict__ out) {
  int row = blockIdx.x, t = threadIdx.x;
  const float4* xr = (const float4*)(x + (size_t)row * 2048);
  float4 a = xr[t], b = xr[t + 256];
  float s  = a.x + a.y + a.z + a.w + b.x + b.y + b.z + b.w;
  float s2 = a.x*a.x + a.y*a.y + a.z*a.z + a.w*a.w
           + b.x*b.x + b.y*b.y + b.z*b.z + b.w*b.w;
#pragma unroll
  for (int off = 32; off >= 1; off >>= 1) {
    s  += __shfl_xor(s, off);
    s2 += __shfl_xor(s2, off);
  }
  __shared__ float red[8];
  if ((t & 63) == 0) { red[t >> 6] = s; red[4 + (t >> 6)] = s2; }
  __syncthreads();
  float S  = red[0] + red[1] + red[2] + red[3];
  float S2 = red[4] + red[5] + red[6] + red[7];
  float mu = S * (1.0f / 2048.0f);
  float var = S2 * (1.0f / 2048.0f) - mu * mu;
  float rstd = rsqrtf(var + 1e-6f);
  const float4* gv = (const float4*)gam;
  const float4* bv = (const float4*)bet;
  float4 g1 = gv[t], g2 = gv[t + 256], c1 = bv[t], c2 = bv[t + 256];
  bf16_t* orow = out + (size_t)row * 2048;
  orow[4*t + 0]    = __float2bfloat16((a.x - mu) * rstd * g1.x + c1.x);
  orow[4*t + 1]    = __float2bfloat16((a.y - mu) * rstd * g1.y + c1.y);
  orow[4*t + 2]    = __float2bfloat16((a.z - mu) * rstd * g1.z + c1.z);
  orow[4*t + 3]    = __float2bfloat16((a.w - mu) * rstd * g1.w + c1.w);
  orow[1024 + 4*t + 0] = __float2bfloat16((b.x - mu) * rstd * g2.x + c2.x);
  orow[1024 + 4*t + 1] = __float2bfloat16((b.y - mu) * rstd * g2.y + c2.y);
  orow[1024 + 4*t + 2] = __float2bfloat16((b.z - mu) * rstd * g2.z + c2.z);
  orow[1024 + 4*t + 3] = __float2bfloat16((b.w - mu) * rstd * g2.w + c2.w);
}

// ---------- R10 8-phase 256x256 GEMM + R12 XCD-resident-B mapping ----------
// Kernel body identical to R10 (best measured: 658us total). Only the block->tile
// mapping changed: XCD x (= blockIdx%8, HW dispatch round-robin) owns n-tiles
// [x*nsub, (x+1)*nsub) -> its B-slice (nsub*256 rows = 1.5-4MB) stays resident in
// the 4MB per-XCD L2 for the whole kernel; m walks INNER so consecutive blocks on
// one XCD reuse the same B-tile. A streams from L3. This halves the bytes pulled
// through the ~10 B/cy/CU global staging path that capped all prior structures.
// EPI: 0 = bf16+bias ; 1 = bf16+bias+gelu ; 3 = f32 atomicAdd (+bias on chunk 0).
template <int EPI>
__global__ __launch_bounds__(512, 2) void k_gemm8(const bf16_t* __restrict__ A,
                                                  const bf16_t* __restrict__ Bt,
                                                  const float* __restrict__ bias,
                                                  bf16_t* __restrict__ Cb,
                                                  float* __restrict__ Cf,
                                                  int Ndim, int LDA, int LDB,
                                                  int Kdim, int nsub) {
  __shared__ __align__(16) char lds[131072];
  int orig = blockIdx.x;
  int xcd = orig & 7;                       // HW: block b dispatches to XCD b%8
  int i = orig >> 3;
  int m = i & 15;                           // M = 4096 -> 16 m-tiles, m INNER
  int j = i >> 4;
  int n_local = j % nsub;
  int chunk = j / nsub;                     // split-K chunk (MLP2)
  int m0 = m * 256;
  int n0 = (xcd * nsub + n_local) * 256;
  int tid = threadIdx.x;
  int w = tid >> 6, lane = tid & 63;
  int lr = lane & 15, lk = lane >> 4;
  int wr = w >> 2, wc = w & 3;

  const bf16_t* Ag = A + (size_t)m0 * LDA + (size_t)chunk * Kdim;
  const bf16_t* Bg = Bt + (size_t)n0 * LDB + (size_t)chunk * Kdim;
  int swch = ((tid & 7) ^ ((tid >> 3) & 7)) << 3;    // elems
  const bf16_t* pA0 = Ag + (size_t)(tid >> 3) * LDA + swch;
  const bf16_t* pA1 = pA0 + (size_t)128 * LDA;
  int nb0 = ((tid >> 8) & 1) * 64 + ((tid >> 3) & 31);
  const bf16_t* pB0 = Bg + (size_t)nb0 * LDB + swch;
  const bf16_t* pB1 = pB0 + (size_t)128 * LDB;
  int dstb = tid * 16;
  int chv0 = ((lk)     ^ (lr & 7)) * 16;
  int chv1 = ((4 + lk) ^ (lr & 7)) * 16;
  int aof0 = 65536 + wr * 8192 + lr * 128 + chv0;
  int aof1 = 65536 + wr * 8192 + lr * 128 + chv1;
  int bof0 = wc * 4096 + lr * 128 + chv0;
  int bof1 = wc * 4096 + lr * 128 + chv1;

  f32x4 acc[8][4];
#pragma unroll
  for (int ii = 0; ii < 8; ++ii)
#pragma unroll
    for (int jj = 0; jj < 4; ++jj) acc[ii][jj] = (f32x4){0.f, 0.f, 0.f, 0.f};
  short8 af[4][2], bq[2][2];

#define STAGE_A(p, h, kt) do { \
    size_t ko = (size_t)(kt) * 64 + (size_t)(h) * 64 * LDA; \
    gload_lds16(pA0 + ko, lds + 65536 + (p) * 32768 + (h) * 16384 + dstb); \
    gload_lds16(pA1 + ko, lds + 65536 + (p) * 32768 + (h) * 16384 + 8192 + dstb); } while (0)
#define STAGE_B(p, h, kt) do { \
    size_t ko = (size_t)(kt) * 64 + (size_t)(h) * 32 * LDB; \
    gload_lds16(pB0 + ko, lds + (p) * 32768 + (h) * 16384 + dstb); \
    gload_lds16(pB1 + ko, lds + (p) * 32768 + (h) * 16384 + 8192 + dstb); } while (0)
#define READ_A(p, mh) do { \
    _Pragma("unroll") for (int mf = 0; mf < 4; ++mf) { \
      af[mf][0] = *(const short8*)(lds + (p) * 32768 + (mh) * 16384 + mf * 2048 + aof0); \
      af[mf][1] = *(const short8*)(lds + (p) * 32768 + (mh) * 16384 + mf * 2048 + aof1); } } while (0)
#define READ_B(p, nh) do { \
    _Pragma("unroll") for (int nf = 0; nf < 2; ++nf) { \
      bq[nf][0] = *(const short8*)(lds + (p) * 32768 + (nh) * 16384 + nf * 2048 + bof0); \
      bq[nf][1] = *(const short8*)(lds + (p) * 32768 + (nh) * 16384 + nf * 2048 + bof1); } } while (0)
#define MM16(mh, nh) do { \
    _Pragma("unroll") for (int ks = 0; ks < 2; ++ks) \
    _Pragma("unroll") for (int mf = 0; mf < 4; ++mf) \
    _Pragma("unroll") for (int nf = 0; nf < 2; ++nf) \
      acc[(mh) * 4 + mf][(nh) * 2 + nf] = __builtin_amdgcn_mfma_f32_16x16x32_bf16( \
          af[mf][ks], bq[nf][ks], acc[(mh) * 4 + mf][(nh) * 2 + nf], 0, 0, 0); } while (0)
#define BARRIER() asm volatile("s_barrier" ::: "memory")
#define LGKM0()  do { asm volatile("s_waitcnt lgkmcnt(0)" ::: "memory"); __builtin_amdgcn_sched_barrier(0); } while (0)
#define PRIO1()  __builtin_amdgcn_s_setprio(1)
#define PRIO0()  __builtin_amdgcn_s_setprio(0)
#define BODY(t, p, S1, S2, VMN) do { \
    READ_A(p, 0); READ_B(p, 0); \
    if (S1) STAGE_B((p) ^ 1, 0, (t) + 1); \
    asm volatile("s_waitcnt lgkmcnt(8)" ::: "memory"); \
    BARRIER(); LGKM0(); PRIO1(); MM16(0, 0); PRIO0(); BARRIER(); \
    READ_B(p, 1); \
    if (S2) STAGE_A(p, 0, (t) + 2); \
    BARRIER(); LGKM0(); PRIO1(); MM16(0, 1); PRIO0(); BARRIER(); \
    READ_A(p, 1); \
    if (S2) STAGE_B(p, 1, (t) + 2); \
    BARRIER(); LGKM0(); PRIO1(); MM16(1, 1); PRIO0(); BARRIER(); \
    READ_B(p, 0); \
    if (S2) STAGE_A(p, 1, (t) + 2); \
    BARRIER(); LGKM0(); PRIO1(); MM16(1, 0); PRIO0(); \
    asm volatile("s_waitcnt vmcnt(%0)" :: "i"(VMN) : "memory"); \
    BARRIER(); } while (0)

  const int NT = Kdim >> 6;                 // even for all our shapes
  STAGE_A(0, 0, 0); STAGE_B(0, 0, 0); STAGE_B(0, 1, 0); STAGE_A(0, 1, 0);
  STAGE_A(1, 0, 1); STAGE_B(1, 1, 1); STAGE_A(1, 1, 1);
  asm volatile("s_waitcnt vmcnt(6)" ::: "memory");
  BARRIER();

  int t = 0;
  for (; t + 3 < NT; t += 2) {
    BODY(t, 0, 1, 1, 6);
    BODY(t + 1, 1, 1, 1, 6);
  }
  BODY(t, 0, 1, 0, 0);
  {
    READ_A(1, 0); READ_B(1, 0);
    BARRIER(); LGKM0(); MM16(0, 0); BARRIER();
    READ_B(1, 1);
    BARRIER(); LGKM0(); MM16(0, 1); BARRIER();
    READ_A(1, 1);
    BARRIER(); LGKM0(); MM16(1, 1); BARRIER();
    READ_B(1, 0);
    LGKM0(); MM16(1, 0);
  }
#undef STAGE_A
#undef STAGE_B
#undef READ_A
#undef READ_B
#undef MM16
#undef BARRIER
#undef LGKM0
#undef PRIO1
#undef PRIO0
#undef BODY

#pragma unroll
  for (int mf = 0; mf < 8; ++mf) {
#pragma unroll
    for (int nf = 0; nf < 4; ++nf) {
#pragma unroll
      for (int r = 0; r < 4; ++r) {
        int rw = m0 + wr * 128 + mf * 16 + lk * 4 + r;
        int cl = n0 + wc * 64 + nf * 16 + lr;
        float v = acc[mf][nf][r];
        size_t gi = (size_t)rw * Ndim + cl;
        if (EPI == 0) {
          Cb[gi] = __float2bfloat16(v + bias[cl]);
        } else if (EPI == 1) {
          float vv = v + bias[cl];
          float u = vv * (vv * vv * 0.044715f + 1.0f) * 0.7978845608028654f;
          float gl = 0.5f * vv * (1.0f + tanhf(u));
          Cb[gi] = __float2bfloat16(gl);
        } else {
          float add = v + (chunk == 0 ? bias[cl] : 0.0f);
          atomicAdd(&Cf[gi], add);
        }
      }
    }
  }
}

// ---------- transpose V slice of qkv into vT[b][h][dh][t] ----------
__global__ __launch_bounds__(256) void k_transpose_v(const bf16_t* __restrict__ qkv,
                                                     bf16_t* __restrict__ vT) {
  __shared__ bf16_t tile[64][72];
  int bid = blockIdx.x;
  int tt = bid & 31;
  int dt = (bid >> 5) & 1;
  int h  = (bid >> 6) & 15;
  int b  = bid >> 10;
  int t0 = tt * 64, d0 = dt * 64;
  int t = threadIdx.x;
  const bf16_t* src = qkv + (size_t)(b * 2048) * 6144 + 4096 + h * 128;
#pragma unroll
  for (int i = 0; i < 16; ++i) {
    int idx = t + i * 256;
    int rr = idx >> 6, cc = idx & 63;
    tile[rr][cc] = src[(size_t)(t0 + rr) * 6144 + d0 + cc];
  }
  __syncthreads();
  bf16_t* dst = vT + (size_t)(b * 16 + h) * 128 * 2048;
#pragma unroll
  for (int i = 0; i < 16; ++i) {
    int idx = t + i * 256;
    int rr = idx >> 6, cc = idx & 63;
    dst[(size_t)(d0 + rr) * 2048 + t0 + cc] = tile[cc][rr];
  }
}

// ---------- causal flash attention + residual add ----------
// R11 pipelined K/V loads (verified) + R12 setprio around MFMA clusters
// (waves are barrier-free/independent -> m191 regime where setprio pays).
__global__ __launch_bounds__(256, 2) void k_attn(const bf16_t* __restrict__ qkv,
                                                 const bf16_t* __restrict__ vT,
                                                 const float* __restrict__ x,
                                                 float* __restrict__ out) {
  __shared__ __align__(16) bf16_t Pl[4][32][40];
  int j = blockIdx.x;
  int bh = j & 31;
  int cq = j >> 5;
  int b = bh >> 4, h = bh & 15;
  int w = threadIdx.x >> 6, lane = threadIdx.x & 63;
  int lr = lane & 15, lk = lane >> 4;
  int c = (w == 0) ? cq : (w == 1) ? (63 - cq) : (w == 2) ? (31 - cq) : (32 + cq);
  int q0 = c * 32;
  const bf16_t* qb = qkv + (size_t)(b * 2048) * 6144 + h * 128;
  const bf16_t* kb = qb + 2048;
  const bf16_t* vb = vT + (size_t)(b * 16 + h) * 128 * 2048;
  short8 qf[2][4];
#pragma unroll
  for (int qg = 0; qg < 2; ++qg)
#pragma unroll
    for (int d4 = 0; d4 < 4; ++d4)
      qf[qg][d4] = *(const short8*)(qb + (size_t)(q0 + qg * 16 + lr) * 6144 + d4 * 32 + lk * 8);
  float m[2][4], l[2][4];
#pragma unroll
  for (int qg = 0; qg < 2; ++qg)
#pragma unroll
    for (int r = 0; r < 4; ++r) { m[qg][r] = -1e30f; l[qg][r] = 0.f; }
  f32x4 o[2][8] = {};
  int nkt = c + 1;
  const float sc = 0.08838834764831845f;
  short8 kf[2][4], vf[8];
#pragma unroll
  for (int nt = 0; nt < 2; ++nt)
#pragma unroll
    for (int d4 = 0; d4 < 4; ++d4)
      kf[nt][d4] = *(const short8*)(kb + (size_t)(nt * 16 + lr) * 6144 + d4 * 32 + lk * 8);
#pragma unroll
  for (int d8 = 0; d8 < 8; ++d8)
    vf[d8] = *(const short8*)(vb + (size_t)(d8 * 16 + lr) * 2048 + lk * 8);

  for (int kt = 0; kt < nkt; ++kt) {
    int tk0 = kt * 32;
    f32x4 s[2][2] = {};
    __builtin_amdgcn_s_setprio(1);
#pragma unroll
    for (int d4 = 0; d4 < 4; ++d4)
#pragma unroll
      for (int qg = 0; qg < 2; ++qg)
#pragma unroll
        for (int nt = 0; nt < 2; ++nt)
          s[qg][nt] = __builtin_amdgcn_mfma_f32_16x16x32_bf16(qf[qg][d4], kf[nt][d4], s[qg][nt], 0, 0, 0);
    __builtin_amdgcn_s_setprio(0);
    if (kt + 1 < nkt) {
      int tn = tk0 + 32;
#pragma unroll
      for (int nt = 0; nt < 2; ++nt)
#pragma unroll
        for (int d4 = 0; d4 < 4; ++d4)
          kf[nt][d4] = *(const short8*)(kb + (size_t)(tn + nt * 16 + lr) * 6144 + d4 * 32 + lk * 8);
    }
#pragma unroll
    for (int qg = 0; qg < 2; ++qg) {
      float sv[2][4], mt[4];
#pragma unroll
      for (int r = 0; r < 4; ++r) {
        int qr = q0 + qg * 16 + lk * 4 + r;
#pragma unroll
        for (int nt = 0; nt < 2; ++nt) {
          float v = s[qg][nt][r] * sc;
          int kc = tk0 + nt * 16 + lr;
          sv[nt][r] = (kc > qr) ? -1e30f : v;
        }
        mt[r] = fmaxf(sv[0][r], sv[1][r]);
      }
#pragma unroll
      for (int off = 1; off < 16; off <<= 1)
#pragma unroll
        for (int r = 0; r < 4; ++r) mt[r] = fmaxf(mt[r], __shfl_xor(mt[r], off));
      float alpha[4], rs[4];
#pragma unroll
      for (int r = 0; r < 4; ++r) {
        float mn = fmaxf(m[qg][r], mt[r]);
        alpha[r] = __expf(m[qg][r] - mn);
        m[qg][r] = mn;
      }
#pragma unroll
      for (int r = 0; r < 4; ++r) {
        float p0 = __expf(sv[0][r] - m[qg][r]);
        float p1 = __expf(sv[1][r] - m[qg][r]);
        rs[r] = p0 + p1;
        Pl[w][qg * 16 + lk * 4 + r][lr]      = __float2bfloat16(p0);
        Pl[w][qg * 16 + lk * 4 + r][16 + lr] = __float2bfloat16(p1);
      }
#pragma unroll
      for (int off = 1; off < 16; off <<= 1)
#pragma unroll
        for (int r = 0; r < 4; ++r) rs[r] += __shfl_xor(rs[r], off);
#pragma unroll
      for (int r = 0; r < 4; ++r) l[qg][r] = l[qg][r] * alpha[r] + rs[r];
#pragma unroll
      for (int d8 = 0; d8 < 8; ++d8)
#pragma unroll
        for (int r = 0; r < 4; ++r) o[qg][d8][r] *= alpha[r];
    }
    asm volatile("s_waitcnt lgkmcnt(0)" ::: "memory");
    short8 pf[2];
#pragma unroll
    for (int qg = 0; qg < 2; ++qg)
      pf[qg] = *(const short8*)(&Pl[w][qg * 16 + lr][lk * 8]);
    __builtin_amdgcn_s_setprio(1);
#pragma unroll
    for (int d8 = 0; d8 < 8; ++d8)
#pragma unroll
      for (int qg = 0; qg < 2; ++qg)
        o[qg][d8] = __builtin_amdgcn_mfma_f32_16x16x32_bf16(pf[qg], vf[d8], o[qg][d8], 0, 0, 0);
    __builtin_amdgcn_s_setprio(0);
    if (kt + 1 < nkt) {
      int tn = tk0 + 32;
#pragma unroll
      for (int d8 = 0; d8 < 8; ++d8)
        vf[d8] = *(const short8*)(vb + (size_t)(d8 * 16 + lr) * 2048 + tn + lk * 8);
    }
  }
#pragma unroll
  for (int qg = 0; qg < 2; ++qg)
#pragma unroll
    for (int d8 = 0; d8 < 8; ++d8)
#pragma unroll
      for (int r = 0; r < 4; ++r) {
        int qr = q0 + qg * 16 + lk * 4 + r;
        int cl = h * 128 + d8 * 16 + lr;
        size_t gi = (size_t)(b * 2048 + qr) * 2048 + cl;
        out[gi] = x[gi] + o[qg][d8][r] / l[qg][r];
      }
}

extern "C" void kernel_launch(void* const* d_in, const int* in_sizes, int n_in,
                              void* d_out, int out_size, void* d_ws, size_t ws_size,
                              hipStream_t stream) {
  const float* x    = (const float*)d_in[0];
  const float* ln1s = (const float*)d_in[1];
  const float* ln1b = (const float*)d_in[2];
  const float* wqkv = (const float*)d_in[3];
  const float* bqkv = (const float*)d_in[4];
  const float* ln2s = (const float*)d_in[5];
  const float* ln2b = (const float*)d_in[6];
  const float* w1   = (const float*)d_in[7];
  const float* b1   = (const float*)d_in[8];
  const float* w2   = (const float*)d_in[9];
  const float* b2   = (const float*)d_in[10];
  float* out = (float*)d_out;
  char* ws = (char*)d_ws;

  // ws layout (bytes); r/vT share region 0 (disjoint lifetimes), wqkvT aliases h.
  bf16_t* r     = (bf16_t*)(ws + 0);              // 16,777,216  [4096][2048]
  bf16_t* vT    = (bf16_t*)(ws + 0);              // same region [2][16][128][2048]
  bf16_t* qkv   = (bf16_t*)(ws + 16777216);       // 50,331,648  [4096][6144]
  bf16_t* w1T   = (bf16_t*)(ws + 67108864);       // 33,554,432  [8192][2048]
  bf16_t* w2T   = (bf16_t*)(ws + 100663296);      // 33,554,432  [2048][8192]
  bf16_t* h     = (bf16_t*)(ws + 134217728);      // 67,108,864  [4096][8192]
  bf16_t* wqkvT = (bf16_t*)(ws + 134217728);      // 25,165,824  [6144][2048] (dead before h)
  // total required: 201,326,592 bytes

  // weight transposes (f32 [K][N] -> bf16 [N][K]), vectorized
  k_transpose_cvt<<<dim3(96, 32),  256, 0, stream>>>(wqkv, wqkvT, 2048, 6144);
  k_transpose_cvt<<<dim3(128, 32), 256, 0, stream>>>(w1,   w1T,   2048, 8192);
  k_transpose_cvt<<<dim3(32, 128), 256, 0, stream>>>(w2,   w2T,   8192, 2048);
  // LN1
  k_layernorm<<<4096, 256, 0, stream>>>(x, ln1s, ln1b, r);
  // QKV: 24 n-tiles -> nsub=3 per XCD (B-slice 3MB L2-resident); 384 blocks
  k_gemm8<0><<<384, 512, 0, stream>>>(r, wqkvT, bqkv, qkv, nullptr, 6144, 2048, 2048, 2048, 3);
  // V transpose for PV operand
  k_transpose_v<<<2048, 256, 0, stream>>>(qkv, vT);
  // attention + residual (writes every element of d_out)
  k_attn<<<512, 256, 0, stream>>>(qkv, vT, x, out);
  // LN2 on x2 = d_out
  k_layernorm<<<4096, 256, 0, stream>>>(out, ln2s, ln2b, r);
  // MLP1: 32 n-tiles -> nsub=4 (B-slice 4MB L2-resident); 512 blocks
  k_gemm8<1><<<512, 512, 0, stream>>>(r, w1T, b1, h, nullptr, 8192, 2048, 2048, 2048, 4);
  // MLP2 split-K=2, atomicAdd epilogue: 8 n-tiles -> nsub=1 (both K-chunks of the
  // same n-tile land on one XCD -> 4MB B-slice resident); 256 blocks
  k_gemm8<3><<<256, 512, 0, stream>>>(h, w2T, b2, nullptr, out, 2048, 8192, 8192, 4096, 1);
}

// Round 13
// 649.649 us; speedup vs baseline: 1.0918x; 1.0104x over previous
//
#include <hip/hip_runtime.h>
#include <hip/hip_bf16.h>
#include <stdint.h>
#include <stddef.h>

// B=2, T=2048, D=2048, H=16, DH=128, F=8192, M=B*T=4096
using bf16_t = __hip_bfloat16;
typedef __attribute__((ext_vector_type(8))) short short8;
typedef __attribute__((ext_vector_type(4))) short short4v;
typedef __attribute__((ext_vector_type(4))) float f32x4;

__device__ __forceinline__ void gload_lds16(const void* g, void* l) {
  __builtin_amdgcn_global_load_lds((const __attribute__((address_space(1))) void*)g,
                                   (__attribute__((address_space(3))) void*)l,
                                   16, 0, 0);
}

// ---------- transpose + f32->bf16 convert: out[N][K] = in[K][N] ----------
__global__ __launch_bounds__(256) void k_transpose_cvt(const float* __restrict__ in,
                                                       bf16_t* __restrict__ out,
                                                       int K, int N) {
  __shared__ float tile[64][65];
  int n0 = blockIdx.x * 64, k0 = blockIdx.y * 64;
  int t = threadIdx.x;
  int tr = t >> 4, tc = t & 15;
#pragma unroll
  for (int i = 0; i < 4; ++i) {
    float4 v = *(const float4*)(in + (size_t)(k0 + tr + i * 16) * N + n0 + tc * 4);
    tile[tr + i * 16][tc * 4 + 0] = v.x;
    tile[tr + i * 16][tc * 4 + 1] = v.y;
    tile[tr + i * 16][tc * 4 + 2] = v.z;
    tile[tr + i * 16][tc * 4 + 3] = v.w;
  }
  __syncthreads();
#pragma unroll
  for (int i = 0; i < 4; ++i) {
    int nn = tr + i * 16;
    short4v s;
    s[0] = (short)__bfloat16_as_ushort(__float2bfloat16(tile[tc * 4 + 0][nn]));
    s[1] = (short)__bfloat16_as_ushort(__float2bfloat16(tile[tc * 4 + 1][nn]));
    s[2] = (short)__bfloat16_as_ushort(__float2bfloat16(tile[tc * 4 + 2][nn]));
    s[3] = (short)__bfloat16_as_ushort(__float2bfloat16(tile[tc * 4 + 3][nn]));
    *(short4v*)(out + (size_t)(n0 + nn) * K + k0 + tc * 4) = s;
  }
}

// ---------- layernorm f32 -> bf16, one block per row of 2048 ----------
__global__ __launch_bounds__(256) void k_layernorm(const float* __restrict__ x,
                                                   const float* __restrict__ gam,
                                                   const float* __restrict__ bet,
                                                   bf16_t* __restrict__ out) {
  int row = blockIdx.x, t = threadIdx.x;
  const float4* xr = (const float4*)(x + (size_t)row * 2048);
  float4 a = xr[t], b = xr[t + 256];
  float s  = a.x + a.y + a.z + a.w + b.x + b.y + b.z + b.w;
  float s2 = a.x*a.x + a.y*a.y + a.z*a.z + a.w*a.w
           + b.x*b.x + b.y*b.y + b.z*b.z + b.w*b.w;
#pragma unroll
  for (int off = 32; off >= 1; off >>= 1) {
    s  += __shfl_xor(s, off);
    s2 += __shfl_xor(s2, off);
  }
  __shared__ float red[8];
  if ((t & 63) == 0) { red[t >> 6] = s; red[4 + (t >> 6)] = s2; }
  __syncthreads();
  float S  = red[0] + red[1] + red[2] + red[3];
  float S2 = red[4] + red[5] + red[6] + red[7];
  float mu = S * (1.0f / 2048.0f);
  float var = S2 * (1.0f / 2048.0f) - mu * mu;
  float rstd = rsqrtf(var + 1e-6f);
  const float4* gv = (const float4*)gam;
  const float4* bv = (const float4*)bet;
  float4 g1 = gv[t], g2 = gv[t + 256], c1 = bv[t], c2 = bv[t + 256];
  bf16_t* orow = out + (size_t)row * 2048;
  orow[4*t + 0]    = __float2bfloat16((a.x - mu) * rstd * g1.x + c1.x);
  orow[4*t + 1]    = __float2bfloat16((a.y - mu) * rstd * g1.y + c1.y);
  orow[4*t + 2]    = __float2bfloat16((a.z - mu) * rstd * g1.z + c1.z);
  orow[4*t + 3]    = __float2bfloat16((a.w - mu) * rstd * g1.w + c1.w);
  orow[1024 + 4*t + 0] = __float2bfloat16((b.x - mu) * rstd * g2.x + c2.x);
  orow[1024 + 4*t + 1] = __float2bfloat16((b.y - mu) * rstd * g2.y + c2.y);
  orow[1024 + 4*t + 2] = __float2bfloat16((b.z - mu) * rstd * g2.z + c2.z);
  orow[1024 + 4*t + 3] = __float2bfloat16((b.w - mu) * rstd * g2.w + c2.w);
}

// ---------- 8-phase 256x256 GEMM, R13: B-frag register retention ----------
// bq0 (n-lo) loaded once in P1 and kept in registers through P4 -> 24 ds_read_b128
// per K-tile per wave (the minimum), phase 4 is read-free. Staging slots/vmcnt
// schedule identical to R10/R12 (twice verified). XCD-resident-B mapping (R12).
// EPI: 0 = bf16+bias ; 1 = bf16+bias+gelu ; 3 = f32 atomicAdd (+bias on chunk 0);
//      4 = QKV: n0<4096 -> bf16+bias into Cb; n0>=4096 -> packed vT store only.
template <int EPI>
__global__ __launch_bounds__(512, 2) void k_gemm8(const bf16_t* __restrict__ A,
                                                  const bf16_t* __restrict__ Bt,
                                                  const float* __restrict__ bias,
                                                  bf16_t* __restrict__ Cb,
                                                  float* __restrict__ Cf,
                                                  bf16_t* __restrict__ Vt,
                                                  int Ndim, int LDA, int LDB,
                                                  int Kdim, int nsub) {
  __shared__ __align__(16) char lds[131072];
  int orig = blockIdx.x;
  int xcd = orig & 7;
  int i = orig >> 3;
  int m = i & 15;
  int j = i >> 4;
  int n_local = j % nsub;
  int chunk = j / nsub;
  int m0 = m * 256;
  int n0 = (xcd * nsub + n_local) * 256;
  int tid = threadIdx.x;
  int w = tid >> 6, lane = tid & 63;
  int lr = lane & 15, lk = lane >> 4;
  int wr = w >> 2, wc = w & 3;

  const bf16_t* Ag = A + (size_t)m0 * LDA + (size_t)chunk * Kdim;
  const bf16_t* Bg = Bt + (size_t)n0 * LDB + (size_t)chunk * Kdim;
  int swch = ((tid & 7) ^ ((tid >> 3) & 7)) << 3;
  const bf16_t* pA0 = Ag + (size_t)(tid >> 3) * LDA + swch;
  const bf16_t* pA1 = pA0 + (size_t)128 * LDA;
  int nb0 = ((tid >> 8) & 1) * 64 + ((tid >> 3) & 31);
  const bf16_t* pB0 = Bg + (size_t)nb0 * LDB + swch;
  const bf16_t* pB1 = pB0 + (size_t)128 * LDB;
  int dstb = tid * 16;
  int chv0 = ((lk)     ^ (lr & 7)) * 16;
  int chv1 = ((4 + lk) ^ (lr & 7)) * 16;
  int aof0 = 65536 + wr * 8192 + lr * 128 + chv0;
  int aof1 = 65536 + wr * 8192 + lr * 128 + chv1;
  int bof0 = wc * 4096 + lr * 128 + chv0;
  int bof1 = wc * 4096 + lr * 128 + chv1;

  f32x4 acc[8][4];
#pragma unroll
  for (int ii = 0; ii < 8; ++ii)
#pragma unroll
    for (int jj = 0; jj < 4; ++jj) acc[ii][jj] = (f32x4){0.f, 0.f, 0.f, 0.f};
  short8 af[4][2], bq0[2][2], bq1[2][2];

#define STAGE_A(p, h, kt) do { \
    size_t ko = (size_t)(kt) * 64 + (size_t)(h) * 64 * LDA; \
    gload_lds16(pA0 + ko, lds + 65536 + (p) * 32768 + (h) * 16384 + dstb); \
    gload_lds16(pA1 + ko, lds + 65536 + (p) * 32768 + (h) * 16384 + 8192 + dstb); } while (0)
#define STAGE_B(p, h, kt) do { \
    size_t ko = (size_t)(kt) * 64 + (size_t)(h) * 32 * LDB; \
    gload_lds16(pB0 + ko, lds + (p) * 32768 + (h) * 16384 + dstb); \
    gload_lds16(pB1 + ko, lds + (p) * 32768 + (h) * 16384 + 8192 + dstb); } while (0)
#define READ_A(p, mh) do { \
    _Pragma("unroll") for (int mf = 0; mf < 4; ++mf) { \
      af[mf][0] = *(const short8*)(lds + (p) * 32768 + (mh) * 16384 + mf * 2048 + aof0); \
      af[mf][1] = *(const short8*)(lds + (p) * 32768 + (mh) * 16384 + mf * 2048 + aof1); } } while (0)
#define READ_B0(p) do { \
    _Pragma("unroll") for (int nf = 0; nf < 2; ++nf) { \
      bq0[nf][0] = *(const short8*)(lds + (p) * 32768 + nf * 2048 + bof0); \
      bq0[nf][1] = *(const short8*)(lds + (p) * 32768 + nf * 2048 + bof1); } } while (0)
#define READ_B1(p) do { \
    _Pragma("unroll") for (int nf = 0; nf < 2; ++nf) { \
      bq1[nf][0] = *(const short8*)(lds + (p) * 32768 + 16384 + nf * 2048 + bof0); \
      bq1[nf][1] = *(const short8*)(lds + (p) * 32768 + 16384 + nf * 2048 + bof1); } } while (0)
#define MM16(mh, nh) do { \
    _Pragma("unroll") for (int ks = 0; ks < 2; ++ks) \
    _Pragma("unroll") for (int mf = 0; mf < 4; ++mf) \
    _Pragma("unroll") for (int nf = 0; nf < 2; ++nf) \
      acc[(mh) * 4 + mf][(nh) * 2 + nf] = __builtin_amdgcn_mfma_f32_16x16x32_bf16( \
          af[mf][ks], (nh) ? bq1[nf][ks] : bq0[nf][ks], \
          acc[(mh) * 4 + mf][(nh) * 2 + nf], 0, 0, 0); } while (0)
#define BARRIER() asm volatile("s_barrier" ::: "memory")
#define LGKM0()  do { asm volatile("s_waitcnt lgkmcnt(0)" ::: "memory"); __builtin_amdgcn_sched_barrier(0); } while (0)
#define PRIO1()  __builtin_amdgcn_s_setprio(1)
#define PRIO0()  __builtin_amdgcn_s_setprio(0)
#define BODY(t, p, S1, S2, VMN) do { \
    READ_A(p, 0); READ_B0(p); \
    if (S1) STAGE_B((p) ^ 1, 0, (t) + 1); \
    asm volatile("s_waitcnt lgkmcnt(8)" ::: "memory"); \
    BARRIER(); LGKM0(); PRIO1(); MM16(0, 0); PRIO0(); BARRIER(); \
    READ_B1(p); \
    if (S2) STAGE_A(p, 0, (t) + 2); \
    BARRIER(); LGKM0(); PRIO1(); MM16(0, 1); PRIO0(); BARRIER(); \
    READ_A(p, 1); \
    if (S2) STAGE_B(p, 1, (t) + 2); \
    BARRIER(); LGKM0(); PRIO1(); MM16(1, 1); PRIO0(); BARRIER(); \
    if (S2) STAGE_A(p, 1, (t) + 2); \
    BARRIER(); PRIO1(); MM16(1, 0); PRIO0(); \
    asm volatile("s_waitcnt vmcnt(%0)" :: "i"(VMN) : "memory"); \
    BARRIER(); } while (0)

  const int NT = Kdim >> 6;
  STAGE_A(0, 0, 0); STAGE_B(0, 0, 0); STAGE_B(0, 1, 0); STAGE_A(0, 1, 0);
  STAGE_A(1, 0, 1); STAGE_B(1, 1, 1); STAGE_A(1, 1, 1);
  asm volatile("s_waitcnt vmcnt(6)" ::: "memory");
  BARRIER();

  int t = 0;
  for (; t + 3 < NT; t += 2) {
    BODY(t, 0, 1, 1, 6);
    BODY(t + 1, 1, 1, 1, 6);
  }
  BODY(t, 0, 1, 0, 0);
  {
    READ_A(1, 0); READ_B0(1);
    BARRIER(); LGKM0(); MM16(0, 0); BARRIER();
    READ_B1(1);
    BARRIER(); LGKM0(); MM16(0, 1); BARRIER();
    READ_A(1, 1);
    BARRIER(); LGKM0(); MM16(1, 1); BARRIER();
    MM16(1, 0);
  }
#undef STAGE_A
#undef STAGE_B
#undef READ_A
#undef READ_B0
#undef READ_B1
#undef MM16
#undef BARRIER
#undef LGKM0
#undef PRIO1
#undef PRIO0
#undef BODY

  if (EPI == 4 && n0 >= 4096) {
    // V tile of QKV: write ONLY the transposed vT[b][h][dh][t] (packed 4x bf16
    // along t = the 4 accumulator rows). qkv's V region is never read.
#pragma unroll
    for (int mf = 0; mf < 8; ++mf) {
#pragma unroll
      for (int nf = 0; nf < 4; ++nf) {
        int cl = n0 + wc * 64 + nf * 16 + lr;
        int d = cl - 4096;
        int hh = d >> 7, dh = d & 127;
        int rwb = m0 + wr * 128 + mf * 16 + lk * 4;
        int bb = rwb >> 11, tt = rwb & 2047;
        float bs = bias[cl];
        short4v s;
#pragma unroll
        for (int r = 0; r < 4; ++r)
          s[r] = (short)__bfloat16_as_ushort(__float2bfloat16(acc[mf][nf][r] + bs));
        *(short4v*)(Vt + ((size_t)(bb * 16 + hh) * 128 + dh) * 2048 + tt) = s;
      }
    }
    return;
  }
#pragma unroll
  for (int mf = 0; mf < 8; ++mf) {
#pragma unroll
    for (int nf = 0; nf < 4; ++nf) {
#pragma unroll
      for (int r = 0; r < 4; ++r) {
        int rw = m0 + wr * 128 + mf * 16 + lk * 4 + r;
        int cl = n0 + wc * 64 + nf * 16 + lr;
        float v = acc[mf][nf][r];
        size_t gi = (size_t)rw * Ndim + cl;
        if (EPI == 0 || EPI == 4) {
          Cb[gi] = __float2bfloat16(v + bias[cl]);
        } else if (EPI == 1) {
          float vv = v + bias[cl];
          float u = vv * (vv * vv * 0.044715f + 1.0f) * 0.7978845608028654f;
          float gl = 0.5f * vv * (1.0f + tanhf(u));
          Cb[gi] = __float2bfloat16(gl);
        } else {
          float add = v + (chunk == 0 ? bias[cl] : 0.0f);
          atomicAdd(&Cf[gi], add);
        }
      }
    }
  }
}

// ---------- causal flash attention + residual add ----------
// R11 pipelined K/V loads + setprio around MFMA clusters.
__global__ __launch_bounds__(256, 2) void k_attn(const bf16_t* __restrict__ qkv,
                                                 const bf16_t* __restrict__ vT,
                                                 const float* __restrict__ x,
                                                 float* __restrict__ out) {
  __shared__ __align__(16) bf16_t Pl[4][32][40];
  int j = blockIdx.x;
  int bh = j & 31;
  int cq = j >> 5;
  int b = bh >> 4, h = bh & 15;
  int w = threadIdx.x >> 6, lane = threadIdx.x & 63;
  int lr = lane & 15, lk = lane >> 4;
  int c = (w == 0) ? cq : (w == 1) ? (63 - cq) : (w == 2) ? (31 - cq) : (32 + cq);
  int q0 = c * 32;
  const bf16_t* qb = qkv + (size_t)(b * 2048) * 6144 + h * 128;
  const bf16_t* kb = qb + 2048;
  const bf16_t* vb = vT + (size_t)(b * 16 + h) * 128 * 2048;
  short8 qf[2][4];
#pragma unroll
  for (int qg = 0; qg < 2; ++qg)
#pragma unroll
    for (int d4 = 0; d4 < 4; ++d4)
      qf[qg][d4] = *(const short8*)(qb + (size_t)(q0 + qg * 16 + lr) * 6144 + d4 * 32 + lk * 8);
  float m[2][4], l[2][4];
#pragma unroll
  for (int qg = 0; qg < 2; ++qg)
#pragma unroll
    for (int r = 0; r < 4; ++r) { m[qg][r] = -1e30f; l[qg][r] = 0.f; }
  f32x4 o[2][8] = {};
  int nkt = c + 1;
  const float sc = 0.08838834764831845f;
  short8 kf[2][4], vf[8];
#pragma unroll
  for (int nt = 0; nt < 2; ++nt)
#pragma unroll
    for (int d4 = 0; d4 < 4; ++d4)
      kf[nt][d4] = *(const short8*)(kb + (size_t)(nt * 16 + lr) * 6144 + d4 * 32 + lk * 8);
#pragma unroll
  for (int d8 = 0; d8 < 8; ++d8)
    vf[d8] = *(const short8*)(vb + (size_t)(d8 * 16 + lr) * 2048 + lk * 8);

  for (int kt = 0; kt < nkt; ++kt) {
    int tk0 = kt * 32;
    f32x4 s[2][2] = {};
    __builtin_amdgcn_s_setprio(1);
#pragma unroll
    for (int d4 = 0; d4 < 4; ++d4)
#pragma unroll
      for (int qg = 0; qg < 2; ++qg)
#pragma unroll
        for (int nt = 0; nt < 2; ++nt)
          s[qg][nt] = __builtin_amdgcn_mfma_f32_16x16x32_bf16(qf[qg][d4], kf[nt][d4], s[qg][nt], 0, 0, 0);
    __builtin_amdgcn_s_setprio(0);
    if (kt + 1 < nkt) {
      int tn = tk0 + 32;
#pragma unroll
      for (int nt = 0; nt < 2; ++nt)
#pragma unroll
        for (int d4 = 0; d4 < 4; ++d4)
          kf[nt][d4] = *(const short8*)(kb + (size_t)(tn + nt * 16 + lr) * 6144 + d4 * 32 + lk * 8);
    }
#pragma unroll
    for (int qg = 0; qg < 2; ++qg) {
      float sv[2][4], mt[4];
#pragma unroll
      for (int r = 0; r < 4; ++r) {
        int qr = q0 + qg * 16 + lk * 4 + r;
#pragma unroll
        for (int nt = 0; nt < 2; ++nt) {
          float v = s[qg][nt][r] * sc;
          int kc = tk0 + nt * 16 + lr;
          sv[nt][r] = (kc > qr) ? -1e30f : v;
        }
        mt[r] = fmaxf(sv[0][r], sv[1][r]);
      }
#pragma unroll
      for (int off = 1; off < 16; off <<= 1)
#pragma unroll
        for (int r = 0; r < 4; ++r) mt[r] = fmaxf(mt[r], __shfl_xor(mt[r], off));
      float alpha[4], rs[4];
#pragma unroll
      for (int r = 0; r < 4; ++r) {
        float mn = fmaxf(m[qg][r], mt[r]);
        alpha[r] = __expf(m[qg][r] - mn);
        m[qg][r] = mn;
      }
#pragma unroll
      for (int r = 0; r < 4; ++r) {
        float p0 = __expf(sv[0][r] - m[qg][r]);
        float p1 = __expf(sv[1][r] - m[qg][r]);
        rs[r] = p0 + p1;
        Pl[w][qg * 16 + lk * 4 + r][lr]      = __float2bfloat16(p0);
        Pl[w][qg * 16 + lk * 4 + r][16 + lr] = __float2bfloat16(p1);
      }
#pragma unroll
      for (int off = 1; off < 16; off <<= 1)
#pragma unroll
        for (int r = 0; r < 4; ++r) rs[r] += __shfl_xor(rs[r], off);
#pragma unroll
      for (int r = 0; r < 4; ++r) l[qg][r] = l[qg][r] * alpha[r] + rs[r];
#pragma unroll
      for (int d8 = 0; d8 < 8; ++d8)
#pragma unroll
        for (int r = 0; r < 4; ++r) o[qg][d8][r] *= alpha[r];
    }
    asm volatile("s_waitcnt lgkmcnt(0)" ::: "memory");
    short8 pf[2];
#pragma unroll
    for (int qg = 0; qg < 2; ++qg)
      pf[qg] = *(const short8*)(&Pl[w][qg * 16 + lr][lk * 8]);
    __builtin_amdgcn_s_setprio(1);
#pragma unroll
    for (int d8 = 0; d8 < 8; ++d8)
#pragma unroll
      for (int qg = 0; qg < 2; ++qg)
        o[qg][d8] = __builtin_amdgcn_mfma_f32_16x16x32_bf16(pf[qg], vf[d8], o[qg][d8], 0, 0, 0);
    __builtin_amdgcn_s_setprio(0);
    if (kt + 1 < nkt) {
      int tn = tk0 + 32;
#pragma unroll
      for (int d8 = 0; d8 < 8; ++d8)
        vf[d8] = *(const short8*)(vb + (size_t)(d8 * 16 + lr) * 2048 + tn + lk * 8);
    }
  }
#pragma unroll
  for (int qg = 0; qg < 2; ++qg)
#pragma unroll
    for (int d8 = 0; d8 < 8; ++d8)
#pragma unroll
      for (int r = 0; r < 4; ++r) {
        int qr = q0 + qg * 16 + lk * 4 + r;
        int cl = h * 128 + d8 * 16 + lr;
        size_t gi = (size_t)(b * 2048 + qr) * 2048 + cl;
        out[gi] = x[gi] + o[qg][d8][r] / l[qg][r];
      }
}

extern "C" void kernel_launch(void* const* d_in, const int* in_sizes, int n_in,
                              void* d_out, int out_size, void* d_ws, size_t ws_size,
                              hipStream_t stream) {
  const float* x    = (const float*)d_in[0];
  const float* ln1s = (const float*)d_in[1];
  const float* ln1b = (const float*)d_in[2];
  const float* wqkv = (const float*)d_in[3];
  const float* bqkv = (const float*)d_in[4];
  const float* ln2s = (const float*)d_in[5];
  const float* ln2b = (const float*)d_in[6];
  const float* w1   = (const float*)d_in[7];
  const float* b1   = (const float*)d_in[8];
  const float* w2   = (const float*)d_in[9];
  const float* b2   = (const float*)d_in[10];
  float* out = (float*)d_out;
  char* ws = (char*)d_ws;

  // ws layout (bytes):
  //   r     @ 0          16 MB   [4096][2048] bf16   (LN output / GEMM A)
  //   qkv   @ 16 MB      48 MB   [4096][6144] bf16   (V third never written/read)
  //   w1T   @ 64 MB      32 MB
  //   w2T   @ 96 MB      32 MB
  //   h     @ 128 MB     64 MB   (clobbers wqkvT and vT after attention)
  //   wqkvT @ 128 MB     24 MB   (dead before h is written)
  //   vT    @ 160 MB     16 MB   [2][16][128][2048] bf16 (written by QKV epilogue,
  //                               dead before MLP1 writes h)
  bf16_t* r     = (bf16_t*)(ws + 0);
  bf16_t* qkv   = (bf16_t*)(ws + 16777216);
  bf16_t* w1T   = (bf16_t*)(ws + 67108864);
  bf16_t* w2T   = (bf16_t*)(ws + 100663296);
  bf16_t* h     = (bf16_t*)(ws + 134217728);
  bf16_t* wqkvT = (bf16_t*)(ws + 134217728);
  bf16_t* vT    = (bf16_t*)(ws + 167772160);

  // weight transposes (f32 [K][N] -> bf16 [N][K])
  k_transpose_cvt<<<dim3(96, 32),  256, 0, stream>>>(wqkv, wqkvT, 2048, 6144);
  k_transpose_cvt<<<dim3(128, 32), 256, 0, stream>>>(w1,   w1T,   2048, 8192);
  k_transpose_cvt<<<dim3(32, 128), 256, 0, stream>>>(w2,   w2T,   8192, 2048);
  // LN1
  k_layernorm<<<4096, 256, 0, stream>>>(x, ln1s, ln1b, r);
  // QKV (fused V-transpose): 24 n-tiles, nsub=3; 384 blocks
  k_gemm8<4><<<384, 512, 0, stream>>>(r, wqkvT, bqkv, qkv, nullptr, vT, 6144, 2048, 2048, 2048, 3);
  // attention + residual (writes every element of d_out)
  k_attn<<<512, 256, 0, stream>>>(qkv, vT, x, out);
  // LN2 on x2 = d_out
  k_layernorm<<<4096, 256, 0, stream>>>(out, ln2s, ln2b, r);
  // MLP1: 32 n-tiles, nsub=4; 512 blocks
  k_gemm8<1><<<512, 512, 0, stream>>>(r, w1T, b1, h, nullptr, nullptr, 8192, 2048, 2048, 2048, 4);
  // MLP2 split-K=2, atomicAdd epilogue: nsub=1; 256 blocks
  k_gemm8<3><<<256, 512, 0, stream>>>(h, w2T, b2, nullptr, out, nullptr, 2048, 8192, 8192, 4096, 1);
}